// Round 10
// baseline (1083.516 us; speedup 1.0000x reference)
//
#include <hip/hip_runtime.h>

// GroupAwareEncoder: 2-layer graph propagation (LightGCN-style).
//   per layer: h[c] = sum_{i: cols[i]=c} vals[i] * X[rows[i]]      (E x D)
//              Y[r] = sum_{i: rows[i]=r} vals[i] * h[cols[i]]      (N x D)
//              Y    = leaky_relu(Y, slope=0.5)
// Output = final Y (N x D) flat.
//
// R5: fill 8x write-amplified -> fixed in R9 via key-partitioning + nt loads
//     (fill no longer in top-5).
// R9: hist_kernel now #1: 184us, WRITE 150MB for 1MB of counters. Same
//     mechanism: counter lines shared across XCDs + read stream evicting
//     dirty lines -> one writeback per atomic. Fix: partition hist by key
//     range (8-way) + nt COO loads, mirroring the fill fix.

constexpr int D = 64;
constexpr float SLOPE = 0.5f;
constexpr int NPART = 8;

struct Edge { int src; float val; };   // 8 bytes; bit-identical to long long

__device__ __forceinline__ void unpack_edge(long long w, int& src, float& val) {
    src = (int)(unsigned)(w & 0xffffffffLL);
    val = __int_as_float((int)(unsigned)((unsigned long long)w >> 32));
}

// ---------------- partitioned degree histogram ----------------
// Block (part = blockIdx&7, chunk = blockIdx>>3) nt-streams its chunk of the
// COO and increments only counters whose key is in its partition -> each
// counter line is owned by one XCD and stays L2-resident.
__global__ __launch_bounds__(256) void hist_part_kernel(
    const int* __restrict__ rows, const int* __restrict__ cols,
    int* __restrict__ deg_n, int* __restrict__ deg_e,
    int nnz, int SE, int SN)
{
    int part   = blockIdx.x & (NPART - 1);
    int chunk  = blockIdx.x >> 3;
    int nchunk = gridDim.x >> 3;
    int lo_e = part * SE, hi_e = lo_e + SE;
    int lo_n = part * SN, hi_n = lo_n + SN;

    for (int t = chunk * blockDim.x + threadIdx.x; t < nnz;
         t += nchunk * blockDim.x) {
        int c = __builtin_nontemporal_load(cols + t);
        if (c >= lo_e && c < hi_e) atomicAdd(&deg_e[c], 1);
        int r = __builtin_nontemporal_load(rows + t);
        if (r >= lo_n && r < hi_n) atomicAdd(&deg_n[r], 1);
    }
}

// ---------------- 3-phase exclusive scan (1024 elems/block) ----------------

__global__ __launch_bounds__(256) void scan_phase1(
    const int* __restrict__ deg, int* __restrict__ partials, int n)
{
    __shared__ int red[256];
    int tid = threadIdx.x;
    int base = blockIdx.x * 1024 + tid * 4;
    int s = 0;
    #pragma unroll
    for (int k = 0; k < 4; ++k) {
        int i = base + k;
        if (i < n) s += deg[i];
    }
    red[tid] = s;
    __syncthreads();
    for (int d = 128; d > 0; d >>= 1) {
        if (tid < d) red[tid] += red[tid + d];
        __syncthreads();
    }
    if (tid == 0) partials[blockIdx.x] = red[0];
}

__global__ __launch_bounds__(256) void scan_phase2(
    int* __restrict__ partials, int nb, int* __restrict__ off, int n)
{
    __shared__ int part[256];
    int tid = threadIdx.x;
    part[tid] = (tid < nb) ? partials[tid] : 0;
    __syncthreads();
    for (int d = 1; d < 256; d <<= 1) {
        int v = (tid >= d) ? part[tid - d] : 0;
        __syncthreads();
        part[tid] += v;
        __syncthreads();
    }
    if (tid < nb) partials[tid] = (tid == 0) ? 0 : part[tid - 1];
    if (tid == 255) off[n] = part[255];
}

__global__ __launch_bounds__(256) void scan_phase3(
    const int* __restrict__ deg, const int* __restrict__ partials,
    int* __restrict__ off, int* __restrict__ cur, int n)
{
    __shared__ int part[256];
    int tid = threadIdx.x;
    int base = blockIdx.x * 1024 + tid * 4;
    int d0 = 0, d1 = 0, d2 = 0, d3 = 0;
    if (base     < n) d0 = deg[base];
    if (base + 1 < n) d1 = deg[base + 1];
    if (base + 2 < n) d2 = deg[base + 2];
    if (base + 3 < n) d3 = deg[base + 3];
    part[tid] = d0 + d1 + d2 + d3;
    __syncthreads();
    for (int d = 1; d < 256; d <<= 1) {
        int v = (tid >= d) ? part[tid - d] : 0;
        __syncthreads();
        part[tid] += v;
        __syncthreads();
    }
    int p = ((tid == 0) ? 0 : part[tid - 1]) + partials[blockIdx.x];
    if (base     < n) { off[base]     = p; cur[base]     = p; p += d0; }
    if (base + 1 < n) { off[base + 1] = p; cur[base + 1] = p; p += d1; }
    if (base + 2 < n) { off[base + 2] = p; cur[base + 2] = p; p += d2; }
    if (base + 3 < n) { off[base + 3] = p; cur[base + 3] = p; }
}

// ---------------- XCD-partitioned counting-sort fill (one list/pass) -------

__global__ __launch_bounds__(256) void fill_list_kernel(
    const int* __restrict__ key, const int* __restrict__ other,
    const float* __restrict__ vals,
    int* __restrict__ cur, Edge* __restrict__ edges,
    int nnz, int S)
{
    int part   = blockIdx.x & (NPART - 1);
    int chunk  = blockIdx.x >> 3;
    int nchunk = gridDim.x >> 3;
    int lo = part * S, hi = lo + S;

    for (int t = chunk * blockDim.x + threadIdx.x; t < nnz;
         t += nchunk * blockDim.x) {
        int k = __builtin_nontemporal_load(key + t);
        if (k >= lo && k < hi) {
            int   o = __builtin_nontemporal_load(other + t);
            float v = __builtin_nontemporal_load(vals + t);
            int p = atomicAdd(&cur[k], 1);
            Edge e; e.src = o; e.val = v;
            edges[p] = e;                    // normal store: accumulate in L2
        }
    }
}

// ---------------- gather-side SpMM ----------------
// One wave64 per output row; lane owns one dim; register accumulate.
__global__ __launch_bounds__(256) void spmm_gather(
    const int* __restrict__ off, const Edge* __restrict__ edges,
    const float* __restrict__ X, float* __restrict__ out,
    int nrows, int leaky)
{
    int wid = (blockIdx.x * blockDim.x + threadIdx.x) >> 6;
    if (wid >= nrows) return;
    int lane = threadIdx.x & 63;

    const long long* ew = reinterpret_cast<const long long*>(edges);

    int b = __builtin_nontemporal_load(off + wid);
    int e = __builtin_nontemporal_load(off + wid + 1);
    float acc = 0.f;
    int i = b;
    for (; i + 4 <= e; i += 4) {
        long long w0 = __builtin_nontemporal_load(ew + i);
        long long w1 = __builtin_nontemporal_load(ew + i + 1);
        long long w2 = __builtin_nontemporal_load(ew + i + 2);
        long long w3 = __builtin_nontemporal_load(ew + i + 3);
        int s0, s1, s2, s3; float v0, v1, v2, v3;
        unpack_edge(w0, s0, v0);
        unpack_edge(w1, s1, v1);
        unpack_edge(w2, s2, v2);
        unpack_edge(w3, s3, v3);
        float x0 = X[(size_t)s0 * D + lane];
        float x1 = X[(size_t)s1 * D + lane];
        float x2 = X[(size_t)s2 * D + lane];
        float x3 = X[(size_t)s3 * D + lane];
        acc += v0 * x0;
        acc += v1 * x1;
        acc += v2 * x2;
        acc += v3 * x3;
    }
    for (; i < e; ++i) {
        long long w0 = __builtin_nontemporal_load(ew + i);
        int s0; float v0;
        unpack_edge(w0, s0, v0);
        acc += v0 * X[(size_t)s0 * D + lane];
    }
    if (leaky) acc = acc >= 0.f ? acc : SLOPE * acc;
    out[(size_t)wid * D + lane] = acc;
}

// ---------------- launch ----------------

extern "C" void kernel_launch(void* const* d_in, const int* in_sizes, int n_in,
                              void* d_out, int out_size, void* d_ws, size_t ws_size,
                              hipStream_t stream)
{
    const float* ego  = (const float*)d_in[0];   // N x D
    const float* vals = (const float*)d_in[1];   // NNZ
    const int*   rows = (const int*)d_in[2];     // NNZ, in [0, N)
    const int*   cols = (const int*)d_in[3];     // NNZ, in [0, E)

    const int nnz = in_sizes[1];                 // 2,400,000
    const int N   = out_size / D;                // 150,000
    const int E   = 100000;                      // n_edges

    float* outf = (float*)d_out;

    auto align16 = [](size_t x) { return (x + 15) & ~(size_t)15; };
    size_t o = 0;
    size_t edges_e_off = o; o += align16((size_t)nnz * sizeof(Edge));
    size_t edges_n_off = o; o += align16((size_t)nnz * sizeof(Edge));
    size_t off_e_off   = o; o += align16((size_t)(E + 1) * sizeof(int));
    size_t off_n_off   = o; o += align16((size_t)(N + 1) * sizeof(int));
    size_t cur_e_off   = o; o += align16((size_t)E * sizeof(int));
    size_t cur_n_off   = o; o += align16((size_t)N * sizeof(int));
    size_t part_e_off  = o; o += align16(256 * sizeof(int));
    size_t part_n_off  = o; o += align16(256 * sizeof(int));
    size_t h_off       = o; o += align16((size_t)E * D * sizeof(float));
    size_t embs_off    = o; o += align16((size_t)N * D * sizeof(float));
    size_t need = o;

    char* ws = (char*)d_ws;

    if (ws_size >= need) {
        Edge*  edges_e = (Edge*)(ws + edges_e_off);
        Edge*  edges_n = (Edge*)(ws + edges_n_off);
        int*   off_e   = (int*)(ws + off_e_off);
        int*   off_n   = (int*)(ws + off_n_off);
        int*   cur_e   = (int*)(ws + cur_e_off);
        int*   cur_n   = (int*)(ws + cur_n_off);
        int*   part_e  = (int*)(ws + part_e_off);
        int*   part_n  = (int*)(ws + part_n_off);
        float* h       = (float*)(ws + h_off);
        float* embs    = (float*)(ws + embs_off);

        const int nb_sc_e = (E + 1023) / 1024;   // 98
        const int nb_sc_n = (N + 1023) / 1024;   // 147

        const int SE = (E + NPART - 1) / NPART;  // 12500
        const int SN = (N + NPART - 1) / NPART;  // 18750

        (void)hipMemsetAsync(cur_e, 0, (size_t)E * sizeof(int), stream);
        (void)hipMemsetAsync(cur_n, 0, (size_t)N * sizeof(int), stream);
        hist_part_kernel<<<1024, 256, 0, stream>>>(rows, cols, cur_n, cur_e,
                                                   nnz, SE, SN);

        scan_phase1<<<nb_sc_e, 256, 0, stream>>>(cur_e, part_e, E);
        scan_phase1<<<nb_sc_n, 256, 0, stream>>>(cur_n, part_n, N);
        scan_phase2<<<1, 256, 0, stream>>>(part_e, nb_sc_e, off_e, E);
        scan_phase2<<<1, 256, 0, stream>>>(part_n, nb_sc_n, off_n, N);
        scan_phase3<<<nb_sc_e, 256, 0, stream>>>(cur_e, part_e, off_e, cur_e, E);
        scan_phase3<<<nb_sc_n, 256, 0, stream>>>(cur_n, part_n, off_n, cur_n, N);

        // two fill passes: dirty region 2.4MB/XCD each, nt-protected
        fill_list_kernel<<<1024, 256, 0, stream>>>(cols, rows, vals,
                                                   cur_e, edges_e, nnz, SE);
        fill_list_kernel<<<1024, 256, 0, stream>>>(rows, cols, vals,
                                                   cur_n, edges_n, nnz, SN);

        const int nb_spmm_e = (E * 64 + 255) / 256;
        const int nb_spmm_n = (N * 64 + 255) / 256;

        const float* X = ego;
        for (int layer = 0; layer < 2; ++layer) {
            float* Y = (layer == 0) ? embs : outf;
            spmm_gather<<<nb_spmm_e, 256, 0, stream>>>(off_e, edges_e, X, h, E, 0);
            spmm_gather<<<nb_spmm_n, 256, 0, stream>>>(off_n, edges_n, h, Y, N, 1);
            X = Y;
        }
    } else {
        // safety net (ws was sufficient in rounds 4-9): zero the output
        (void)hipMemsetAsync(outf, 0, (size_t)out_size * sizeof(float), stream);
    }
}

// Round 12
// 914.580 us; speedup vs baseline: 1.1847x; 1.1847x over previous
//
#include <hip/hip_runtime.h>

// GroupAwareEncoder: 2-layer graph propagation (LightGCN-style).
//   per layer: h[c] = sum_{i: cols[i]=c} vals[i] * X[rows[i]]      (E x D)
//              Y[r] = sum_{i: rows[i]=r} vals[i] * h[cols[i]]      (N x D)
//              Y    = leaky_relu(Y, slope=0.5)
//
// R10 falsified the L2-locality theory: global atomics write ~64B to HBM per
// edge REGARDLESS of partitioning (memory-side execution). So the CSR build
// is redesigned with ZERO per-edge global atomics:
//   A) per-block LDS bucket histogram (bucket = key>>7) -> cnt[bucket][block]
//   B) exclusive scan (existing 3-phase) over flat bucket-major cnt -> bases
//   C) re-stream chunk, scatter {key,edge} to reserved contiguous segments
//      via LDS cursors (binned array is globally bucket-contiguous)
//   D) one block per bucket: LDS per-key count+scan -> off[] + sorted edges[]
// Only LDS atomics remain. Binned scratch aliases h+embs (dead until spmm).

constexpr int D = 64;
constexpr float SLOPE = 0.5f;
constexpr int NBLK  = 192;   // chunking blocks for A/C (must match exactly)
constexpr int BSH   = 7;     // 128 keys per bucket
constexpr int NBMAX = 1280;  // >= max #buckets (1172 for N=150000)

struct Edge { int src; float val; };

__device__ __forceinline__ void unpack_edge(long long w, int& src, float& val) {
    src = (int)(unsigned)(w & 0xffffffffLL);
    val = __int_as_float((int)(unsigned)((unsigned long long)w >> 32));
}

// ---------------- A: per-block LDS bucket histogram ----------------
__global__ __launch_bounds__(256) void bin_count_kernel(
    const int* __restrict__ key, int* __restrict__ cnt_flat, int nnz, int NB)
{
    __shared__ int cnt[NBMAX];
    int tid = threadIdx.x, blk = blockIdx.x;
    for (int b = tid; b < NB; b += 256) cnt[b] = 0;
    __syncthreads();
    for (int t = blk * 256 + tid; t < nnz; t += NBLK * 256) {
        int k = __builtin_nontemporal_load(key + t);
        atomicAdd(&cnt[k >> BSH], 1);            // LDS atomic
    }
    __syncthreads();
    for (int b = tid; b < NB; b += 256)
        cnt_flat[(size_t)b * NBLK + blk] = cnt[b];
}

// ---------------- 3-phase exclusive scan (1024 elems/block) ----------------
__global__ __launch_bounds__(256) void scan_phase1(
    const int* __restrict__ deg, int* __restrict__ partials, int n)
{
    __shared__ int red[256];
    int tid = threadIdx.x;
    int base = blockIdx.x * 1024 + tid * 4;
    int s = 0;
    #pragma unroll
    for (int k = 0; k < 4; ++k) {
        int i = base + k;
        if (i < n) s += deg[i];
    }
    red[tid] = s;
    __syncthreads();
    for (int d = 128; d > 0; d >>= 1) {
        if (tid < d) red[tid] += red[tid + d];
        __syncthreads();
    }
    if (tid == 0) partials[blockIdx.x] = red[0];
}

__global__ __launch_bounds__(256) void scan_phase2(
    int* __restrict__ partials, int nb)
{
    __shared__ int part[256];
    int tid = threadIdx.x;
    part[tid] = (tid < nb) ? partials[tid] : 0;
    __syncthreads();
    for (int d = 1; d < 256; d <<= 1) {
        int v = (tid >= d) ? part[tid - d] : 0;
        __syncthreads();
        part[tid] += v;
        __syncthreads();
    }
    if (tid < nb) partials[tid] = (tid == 0) ? 0 : part[tid - 1];
}

__global__ __launch_bounds__(256) void scan_phase3(
    const int* __restrict__ deg, const int* __restrict__ partials,
    int* __restrict__ out, int n)
{
    __shared__ int part[256];
    int tid = threadIdx.x;
    int base = blockIdx.x * 1024 + tid * 4;
    int d0 = 0, d1 = 0, d2 = 0, d3 = 0;
    if (base     < n) d0 = deg[base];
    if (base + 1 < n) d1 = deg[base + 1];
    if (base + 2 < n) d2 = deg[base + 2];
    if (base + 3 < n) d3 = deg[base + 3];
    part[tid] = d0 + d1 + d2 + d3;
    __syncthreads();
    for (int d = 1; d < 256; d <<= 1) {
        int v = (tid >= d) ? part[tid - d] : 0;
        __syncthreads();
        part[tid] += v;
        __syncthreads();
    }
    int p = ((tid == 0) ? 0 : part[tid - 1]) + partials[blockIdx.x];
    if (base     < n) { out[base]     = p; p += d0; }
    if (base + 1 < n) { out[base + 1] = p; p += d1; }
    if (base + 2 < n) { out[base + 2] = p; p += d2; }
    if (base + 3 < n) { out[base + 3] = p; }
}

// ---------------- C: scatter into bucket-grouped binned arrays -------------
__global__ __launch_bounds__(256) void bin_scatter_kernel(
    const int* __restrict__ key, const int* __restrict__ other,
    const float* __restrict__ vals, const int* __restrict__ base_flat,
    int* __restrict__ bkey, long long* __restrict__ bedge, int nnz, int NB)
{
    __shared__ int cur[NBMAX];
    int tid = threadIdx.x, blk = blockIdx.x;
    for (int b = tid; b < NB; b += 256)
        cur[b] = base_flat[(size_t)b * NBLK + blk];
    __syncthreads();
    for (int t = blk * 256 + tid; t < nnz; t += NBLK * 256) {
        int   k = __builtin_nontemporal_load(key + t);
        int   o = __builtin_nontemporal_load(other + t);
        float v = __builtin_nontemporal_load(vals + t);
        int p = atomicAdd(&cur[k >> BSH], 1);    // LDS atomic
        bkey[p] = k;
        long long w = (long long)((unsigned long long)(unsigned)o |
                                  ((unsigned long long)__float_as_uint(v) << 32));
        bedge[p] = w;
    }
}

// ---------------- D: per-bucket counting sort -> off[] + final edges -------
__global__ __launch_bounds__(256) void bucket_sort_kernel(
    const int* __restrict__ bkey, const long long* __restrict__ bedge,
    const int* __restrict__ base_flat,
    long long* __restrict__ edges, int* __restrict__ off,
    int nnz, int NB, int K)
{
    __shared__ int sc[128];
    __shared__ int cur[128];
    int b = blockIdx.x, tid = threadIdx.x;
    int start = base_flat[(size_t)b * NBLK];
    int end   = (b == NB - 1) ? nnz : base_flat[(size_t)(b + 1) * NBLK];
    int k0 = b << BSH;
    int nk = K - k0; if (nk > 128) nk = 128;

    if (tid < 128) sc[tid] = 0;
    __syncthreads();
    for (int t = start + tid; t < end; t += 256)
        atomicAdd(&sc[bkey[t] - k0], 1);         // LDS per-key count
    __syncthreads();
    // inclusive Hillis-Steele over 128
    for (int d = 1; d < 128; d <<= 1) {
        int add = (tid < 128 && tid >= d) ? sc[tid - d] : 0;
        __syncthreads();
        if (tid < 128) sc[tid] += add;
        __syncthreads();
    }
    if (tid < 128) {
        int loc = (tid == 0) ? 0 : sc[tid - 1];  // exclusive
        if (tid < nk) off[k0 + tid] = start + loc;
        cur[tid] = loc;
    }
    if (b == NB - 1 && tid == 0) off[K] = nnz;
    __syncthreads();
    for (int t = start + tid; t < end; t += 256) {
        int k = bkey[t] - k0;
        long long w = bedge[t];
        int p = atomicAdd(&cur[k], 1);           // LDS atomic
        edges[start + p] = w;                    // store within 24KB region
    }
}

// ---------------- gather-side SpMM (unchanged) ----------------
__global__ __launch_bounds__(256) void spmm_gather(
    const int* __restrict__ off, const long long* __restrict__ ew,
    const float* __restrict__ X, float* __restrict__ out,
    int nrows, int leaky)
{
    int wid = (blockIdx.x * blockDim.x + threadIdx.x) >> 6;
    if (wid >= nrows) return;
    int lane = threadIdx.x & 63;

    int b = __builtin_nontemporal_load(off + wid);
    int e = __builtin_nontemporal_load(off + wid + 1);
    float acc = 0.f;
    int i = b;
    for (; i + 4 <= e; i += 4) {
        long long w0 = __builtin_nontemporal_load(ew + i);
        long long w1 = __builtin_nontemporal_load(ew + i + 1);
        long long w2 = __builtin_nontemporal_load(ew + i + 2);
        long long w3 = __builtin_nontemporal_load(ew + i + 3);
        int s0, s1, s2, s3; float v0, v1, v2, v3;
        unpack_edge(w0, s0, v0);
        unpack_edge(w1, s1, v1);
        unpack_edge(w2, s2, v2);
        unpack_edge(w3, s3, v3);
        float x0 = X[(size_t)s0 * D + lane];
        float x1 = X[(size_t)s1 * D + lane];
        float x2 = X[(size_t)s2 * D + lane];
        float x3 = X[(size_t)s3 * D + lane];
        acc += v0 * x0;
        acc += v1 * x1;
        acc += v2 * x2;
        acc += v3 * x3;
    }
    for (; i < e; ++i) {
        long long w0 = __builtin_nontemporal_load(ew + i);
        int s0; float v0;
        unpack_edge(w0, s0, v0);
        acc += v0 * X[(size_t)s0 * D + lane];
    }
    if (leaky) acc = acc >= 0.f ? acc : SLOPE * acc;
    out[(size_t)wid * D + lane] = acc;
}

// ---------------- launch ----------------

extern "C" void kernel_launch(void* const* d_in, const int* in_sizes, int n_in,
                              void* d_out, int out_size, void* d_ws, size_t ws_size,
                              hipStream_t stream)
{
    const float* ego  = (const float*)d_in[0];   // N x D
    const float* vals = (const float*)d_in[1];   // NNZ
    const int*   rows = (const int*)d_in[2];     // NNZ, in [0, N)
    const int*   cols = (const int*)d_in[3];     // NNZ, in [0, E)

    const int nnz = in_sizes[1];                 // 2,400,000
    const int N   = out_size / D;                // 150,000
    const int E   = 100000;                      // n_edges

    float* outf = (float*)d_out;

    const int NB_E = (E + 127) >> BSH;           // 782
    const int NB_N = (N + 127) >> BSH;           // 1172
    const int L_E  = NB_E * NBLK;                // 150144
    const int L_N  = NB_N * NBLK;                // 225024

    auto align16 = [](size_t x) { return (x + 15) & ~(size_t)15; };
    size_t o = 0;
    size_t edges_e_off = o; o += align16((size_t)nnz * 8);
    size_t edges_n_off = o; o += align16((size_t)nnz * 8);
    size_t off_e_off   = o; o += align16((size_t)(E + 1) * 4);
    size_t off_n_off   = o; o += align16((size_t)(N + 1) * 4);
    size_t cnt_off     = o; o += align16((size_t)L_N * 4);
    size_t base_off    = o; o += align16((size_t)L_N * 4);
    size_t parts_off   = o; o += align16(256 * 4);
    size_t h_off       = o; o += align16((size_t)E * D * 4);   // 25.6MB
    size_t embs_off    = o; o += align16((size_t)N * D * 4);   // 38.4MB
    size_t need = o;

    char* ws = (char*)d_ws;
    if (ws_size < need) {   // safety net; prior rounds confirm ws is larger
        (void)hipMemsetAsync(outf, 0, (size_t)out_size * sizeof(float), stream);
        return;
    }

    long long* edges_e = (long long*)(ws + edges_e_off);
    long long* edges_n = (long long*)(ws + edges_n_off);
    int*   off_e   = (int*)(ws + off_e_off);
    int*   off_n   = (int*)(ws + off_n_off);
    int*   cnt     = (int*)(ws + cnt_off);
    int*   basef   = (int*)(ws + base_off);
    int*   parts   = (int*)(ws + parts_off);
    float* h       = (float*)(ws + h_off);
    float* embs    = (float*)(ws + embs_off);

    // binned scratch aliases h+embs (64MB >= 28.8MB), dead before spmm runs
    int*       bkey  = (int*)(ws + h_off);
    long long* bedge = (long long*)(ws + h_off + align16((size_t)nnz * 4));

    // ---- build e-list (key = cols, keyspace E) ----
    {
        const int G1 = (L_E + 1023) / 1024;      // 147 <= 256
        bin_count_kernel<<<NBLK, 256, 0, stream>>>(cols, cnt, nnz, NB_E);
        scan_phase1<<<G1, 256, 0, stream>>>(cnt, parts, L_E);
        scan_phase2<<<1, 256, 0, stream>>>(parts, G1);
        scan_phase3<<<G1, 256, 0, stream>>>(cnt, parts, basef, L_E);
        bin_scatter_kernel<<<NBLK, 256, 0, stream>>>(cols, rows, vals, basef,
                                                     bkey, bedge, nnz, NB_E);
        bucket_sort_kernel<<<NB_E, 256, 0, stream>>>(bkey, bedge, basef,
                                                     edges_e, off_e, nnz, NB_E, E);
    }
    // ---- build n-list (key = rows, keyspace N) ----
    {
        const int G1 = (L_N + 1023) / 1024;      // 220 <= 256
        bin_count_kernel<<<NBLK, 256, 0, stream>>>(rows, cnt, nnz, NB_N);
        scan_phase1<<<G1, 256, 0, stream>>>(cnt, parts, L_N);
        scan_phase2<<<1, 256, 0, stream>>>(parts, G1);
        scan_phase3<<<G1, 256, 0, stream>>>(cnt, parts, basef, L_N);
        bin_scatter_kernel<<<NBLK, 256, 0, stream>>>(rows, cols, vals, basef,
                                                     bkey, bedge, nnz, NB_N);
        bucket_sort_kernel<<<NB_N, 256, 0, stream>>>(bkey, bedge, basef,
                                                     edges_n, off_n, nnz, NB_N, N);
    }

    // ---- 2 layers of Mᵀ M X with fused leaky on the second spmm ----
    const int nb_spmm_e = (E * 64 + 255) / 256;
    const int nb_spmm_n = (N * 64 + 255) / 256;

    const float* X = ego;
    for (int layer = 0; layer < 2; ++layer) {
        float* Y = (layer == 0) ? embs : outf;
        spmm_gather<<<nb_spmm_e, 256, 0, stream>>>(off_e, edges_e, X, h, E, 0);
        spmm_gather<<<nb_spmm_n, 256, 0, stream>>>(off_n, edges_n, h, Y, N, 1);
        X = Y;
    }
}